// Round 1
// baseline (10488.515 us; speedup 1.0000x reference)
//
#include <hip/hip_runtime.h>
#include <cstdint>
#include <cstddef>

#define S_LEN 256
#define BATCH 64
#define HID   1024
#define GATES 4096   // 4*HID
#define NLAYER 2
#define KSPLIT 4

typedef _Float16 h16;
typedef _Float16 h16x8 __attribute__((ext_vector_type(8)));
typedef float    f32x4 __attribute__((ext_vector_type(4)));

// ---------------------------------------------------------------------------
// G = A @ W^T + (bi + bh).   A: [M][HID] fp32 or fp16 row-major,
// W: [GATES][HID] fp32 row-major, G: [M][GATES] fp32.
// 128x128 tile per WG: 4 waves in 2x2, each wave 64x64 via 4x4 frags of
// mfma_f32_16x16x32_f16. Fragment layout (m89-verified family):
//   A/B frag: lane holds 8 contiguous K elems of row (lane&15), K-block (lane>>4)*8
//   C/D: col = lane&15, row = (lane>>4)*4 + reg
// ---------------------------------------------------------------------------
template<bool AF32>
__global__ __launch_bounds__(256)
void gemm_g_kernel(const void* __restrict__ Aptr,
                   const float* __restrict__ W,
                   const float* __restrict__ bi,
                   const float* __restrict__ bh,
                   float* __restrict__ G)
{
  const int wave = threadIdx.x >> 6, lane = threadIdx.x & 63;
  const int m0 = blockIdx.y * 128 + (wave >> 1) * 64;
  const int n0 = blockIdx.x * 128 + (wave & 1) * 64;
  const int lr = lane & 15, lk = (lane >> 4) * 8;
  f32x4 acc[4][4] = {};
  for (int kb = 0; kb < HID; kb += 32) {
    h16x8 a[4], b[4];
#pragma unroll
    for (int i = 0; i < 4; ++i) {
      const int arow = m0 + i * 16 + lr;
      if constexpr (AF32) {
        const float* p = (const float*)Aptr + (size_t)arow * HID + kb + lk;
        h16x8 v;
#pragma unroll
        for (int j = 0; j < 8; ++j) v[j] = (h16)p[j];
        a[i] = v;
      } else {
        a[i] = *(const h16x8*)((const h16*)Aptr + (size_t)arow * HID + kb + lk);
      }
      const float* q = W + (size_t)(n0 + i * 16 + lr) * HID + kb + lk;
      h16x8 w;
#pragma unroll
      for (int j = 0; j < 8; ++j) w[j] = (h16)q[j];
      b[i] = w;
    }
#pragma unroll
    for (int i = 0; i < 4; ++i)
#pragma unroll
      for (int j = 0; j < 4; ++j)
        acc[i][j] = __builtin_amdgcn_mfma_f32_16x16x32_f16(a[i], b[j], acc[i][j], 0, 0, 0);
  }
  const int rq = (lane >> 4) * 4;
#pragma unroll
  for (int i = 0; i < 4; ++i)
#pragma unroll
    for (int j = 0; j < 4; ++j)
#pragma unroll
      for (int q = 0; q < 4; ++q) {
        const int m = m0 + i * 16 + rq + q;
        const int n = n0 + j * 16 + lr;
        G[(size_t)m * GATES + n] = acc[i][j][q] + bi[n] + bh[n];
      }
}

// ---------------------------------------------------------------------------
// part[ks] = h @ Whh[k-range ks]^T.  h: [64][HID] fp16, Whh: [GATES][HID] fp32.
// grid = (GATES/256, KSPLIT), 4 waves per WG, each wave: 64m x 64n, K-range 256.
// ---------------------------------------------------------------------------
__global__ __launch_bounds__(256)
void step_gemm_kernel(const h16* __restrict__ hmat,
                      const float* __restrict__ Whh,
                      float* __restrict__ part)
{
  const int wave = threadIdx.x >> 6, lane = threadIdx.x & 63;
  const int n0 = blockIdx.x * 256 + wave * 64;
  const int k0 = blockIdx.y * (HID / KSPLIT);
  const int lr = lane & 15, lk = (lane >> 4) * 8;
  f32x4 acc[4][4] = {};
  for (int kb = k0; kb < k0 + HID / KSPLIT; kb += 32) {
    h16x8 a[4], b[4];
#pragma unroll
    for (int i = 0; i < 4; ++i) {
      a[i] = *(const h16x8*)(hmat + (size_t)(i * 16 + lr) * HID + kb + lk);
      const float* q = Whh + (size_t)(n0 + i * 16 + lr) * HID + kb + lk;
      h16x8 w;
#pragma unroll
      for (int j = 0; j < 8; ++j) w[j] = (h16)q[j];
      b[i] = w;
    }
#pragma unroll
    for (int i = 0; i < 4; ++i)
#pragma unroll
      for (int j = 0; j < 4; ++j)
        acc[i][j] = __builtin_amdgcn_mfma_f32_16x16x32_f16(a[i], b[j], acc[i][j], 0, 0, 0);
  }
  float* out = part + (size_t)blockIdx.y * (BATCH * GATES);
  const int rq = (lane >> 4) * 4;
#pragma unroll
  for (int i = 0; i < 4; ++i)
#pragma unroll
    for (int j = 0; j < 4; ++j)
#pragma unroll
      for (int q = 0; q < 4; ++q)
        out[(size_t)(i * 16 + rq + q) * GATES + n0 + j * 16 + lr] = acc[i][j][q];
}

// ---------------------------------------------------------------------------
// gates = G_t + sum_ks part[ks]; activations; c (fp32, in place); h -> fp16.
// one thread per (m, hcol): 65536 threads.
// ---------------------------------------------------------------------------
__global__ __launch_bounds__(256)
void step_elem_kernel(const float* __restrict__ G,     // [64][GATES] (this t)
                      const float* __restrict__ part,  // [KSPLIT][64][GATES]
                      float* __restrict__ c,           // [64][HID]
                      h16* __restrict__ h_out)         // [64][HID]
{
  const int idx = blockIdx.x * blockDim.x + threadIdx.x;   // 0..65535
  const int m = idx >> 10, j = idx & (HID - 1);
  float g4[4];
#pragma unroll
  for (int g = 0; g < 4; ++g) {
    const size_t r = (size_t)m * GATES + g * HID + j;
    float v = G[r];
#pragma unroll
    for (int ks = 0; ks < KSPLIT; ++ks) v += part[(size_t)ks * BATCH * GATES + r];
    g4[g] = v;
  }
  const float ig = 1.0f / (1.0f + expf(-g4[0]));
  const float fg = 1.0f / (1.0f + expf(-g4[1]));
  const float gg = tanhf(g4[2]);
  const float og = 1.0f / (1.0f + expf(-g4[3]));
  const float cn = fg * c[idx] + ig * gg;
  c[idx] = cn;
  h_out[idx] = (h16)(og * tanhf(cn));
}

// ---------------------------------------------------------------------------
// out[m][cls] = h[m] . fc_w[cls] + fc_b[cls].  One wave per output (640 waves).
// ---------------------------------------------------------------------------
__global__ __launch_bounds__(256)
void fc_kernel(const h16* __restrict__ h,
               const float* __restrict__ fw,
               const float* __restrict__ fb,
               float* __restrict__ out)
{
  const int gw = (blockIdx.x * blockDim.x + threadIdx.x) >> 6;
  const int lane = threadIdx.x & 63;
  if (gw >= BATCH * 10) return;
  const int m = gw / 10, cls = gw % 10;
  float s = 0.f;
  for (int k = lane; k < HID; k += 64)
    s += (float)h[(size_t)m * HID + k] * fw[(size_t)cls * HID + k];
#pragma unroll
  for (int off = 32; off; off >>= 1) s += __shfl_down(s, off);
  if (lane == 0) out[m * 10 + cls] = s + fb[cls];
}

// ---------------------------------------------------------------------------
extern "C" void kernel_launch(void* const* d_in, const int* in_sizes, int n_in,
                              void* d_out, int out_size, void* d_ws, size_t ws_size,
                              hipStream_t stream)
{
  const float* x      = (const float*)d_in[0];   // [256][64][1024]
  const float* weight = (const float*)d_in[1];   // [2][2][4096][1024]
  const float* bias   = (const float*)d_in[2];   // [2][2][4096]
  const float* fc_w   = (const float*)d_in[3];   // [10][1024]
  const float* fc_b   = (const float*)d_in[4];   // [10]
  float* out = (float*)d_out;                    // [64][10]

  auto align = [](size_t v) { return (v + 255) & ~(size_t)255; };

  const size_t xb_sz   = (size_t)S_LEN * BATCH * HID * sizeof(h16);
  const size_t part_sz = (size_t)KSPLIT * BATCH * GATES * sizeof(float);
  const size_t hv_sz   = (size_t)BATCH * HID * sizeof(h16);
  const size_t c_sz    = (size_t)BATCH * HID * sizeof(float);
  const size_t fixed   = align(xb_sz) + align(part_sz) + 3 * align(hv_sz) + align(c_sz);

  int CH = 32;  // G ring depth (timesteps); must be even and divide 256
  while (CH > 2 && fixed + align((size_t)CH * BATCH * GATES * sizeof(float)) > ws_size)
    CH >>= 1;

  char* p = (char*)d_ws;
  h16*   Xb    = (h16*)p;   p += align(xb_sz);                                   // layer0 h-seq / layer1 input
  float* Gring = (float*)p; p += align((size_t)CH * BATCH * GATES * sizeof(float));
  float* part  = (float*)p; p += align(part_sz);
  h16*   h_a   = (h16*)p;   p += align(hv_sz);
  h16*   h_b   = (h16*)p;   p += align(hv_sz);
  h16*   zbuf  = (h16*)p;   p += align(hv_sz);
  float* cbuf  = (float*)p; p += align(c_sz);

  hipMemsetAsync(zbuf, 0, hv_sz, stream);

  for (int layer = 0; layer < NLAYER; ++layer) {
    hipMemsetAsync(cbuf, 0, c_sz, stream);
    const float* Wih = weight + (size_t)layer * 2 * GATES * HID;
    const float* Whh = Wih + (size_t)GATES * HID;
    const float* bi  = bias + (size_t)layer * 2 * GATES;
    const float* bh  = bi + GATES;
    const int nchunk = S_LEN / CH;
    for (int ch = 0; ch < nchunk; ++ch) {
      dim3 gg(GATES / 128, (CH * BATCH) / 128);
      if (layer == 0)
        gemm_g_kernel<true><<<gg, 256, 0, stream>>>(
            x + (size_t)ch * CH * BATCH * HID, Wih, bi, bh, Gring);
      else
        gemm_g_kernel<false><<<gg, 256, 0, stream>>>(
            Xb + (size_t)ch * CH * BATCH * HID, Wih, bi, bh, Gring);
      for (int tl = 0; tl < CH; ++tl) {
        const int t = ch * CH + tl;
        const h16* hprev;
        h16* hout;
        if (layer == 0) {
          hprev = (t == 0) ? zbuf : Xb + (size_t)(t - 1) * BATCH * HID;
          hout  = Xb + (size_t)t * BATCH * HID;
        } else {
          hprev = (t == 0) ? zbuf : ((t & 1) ? h_a : h_b);
          hout  = (t & 1) ? h_b : h_a;
        }
        step_gemm_kernel<<<dim3(GATES / 256, KSPLIT), 256, 0, stream>>>(hprev, Whh, part);
        step_elem_kernel<<<dim3((BATCH * HID) / 256), 256, 0, stream>>>(
            Gring + (size_t)tl * BATCH * GATES, part, cbuf, hout);
      }
    }
  }
  // final h of top layer: t=255 (odd) -> h_b
  fc_kernel<<<dim3((BATCH * 10 * 64) / 256), 256, 0, stream>>>(h_b, fc_w, fc_b, out);
}

// Round 3
// 5377.819 us; speedup vs baseline: 1.9503x; 1.9503x over previous
//
#include <hip/hip_runtime.h>
#include <cstdint>
#include <cstddef>

#define S_LEN 256
#define BATCH 64
#define HID   1024
#define GATES 4096
#define NBLK  256

typedef _Float16 h16;
typedef _Float16 h16x8 __attribute__((ext_vector_type(8)));
typedef _Float16 h16x4 __attribute__((ext_vector_type(4)));
typedef float    f32x4 __attribute__((ext_vector_type(4)));

// ---------------------------------------------------------------------------
// x fp32 -> fp16 (one pass)
// ---------------------------------------------------------------------------
__global__ __launch_bounds__(256)
void xconv_kernel(const float* __restrict__ x, h16* __restrict__ x16)
{
  const int n4 = S_LEN * BATCH * HID / 4;
  const int stride = gridDim.x * 256;
  for (int i = blockIdx.x * 256 + threadIdx.x; i < n4; i += stride) {
    f32x4 v = ((const f32x4*)x)[i];
    h16x4 o;
    o[0] = (h16)v[0]; o[1] = (h16)v[1]; o[2] = (h16)v[2]; o[3] = (h16)v[3];
    ((h16x4*)x16)[i] = o;
  }
}

// ---------------------------------------------------------------------------
// Custom device-scope grid barrier (no cooperative API).
// Monotone counter: step g completes when bar reaches (g+1)*NBLK.
// RELEASE on arrive flushes this XCD's L2; __threadfence on depart
// invalidates L1/L2 so next step's reads see remote writes.
// ---------------------------------------------------------------------------
__device__ __forceinline__ void grid_barrier(unsigned* bar, int g)
{
  __syncthreads();                     // all waves' stores drained (vmcnt before s_barrier)
  if (threadIdx.x == 0) {
    __hip_atomic_fetch_add(bar, 1u, __ATOMIC_RELEASE, __HIP_MEMORY_SCOPE_AGENT);
    const unsigned tgt = (unsigned)(g + 1) * (unsigned)NBLK;
    while (__hip_atomic_load(bar, __ATOMIC_RELAXED, __HIP_MEMORY_SCOPE_AGENT) < tgt)
      __builtin_amdgcn_s_sleep(2);
    __threadfence();                   // acquire: invalidate stale L1/L2 lines
  }
  __syncthreads();
}

// ---------------------------------------------------------------------------
// Persistent 2-layer pipelined LSTM. 256 WGs x 256 thr (1 per CU).
// WG wg: layer = wg>>7, owns hidden cols j0..j0+7 (32 gate-cols).
// Weights (K=2048 = [W_ih | W_hh]) packed fp16 in 128KB LDS, loaded once.
// Step g: layer0 computes t=g (g<256), layer1 computes t=g-1 (g>=1).
// Wave w covers K-slice w*512..: waves 0-1 input part, waves 2-3 hidden part.
// Cross-wave K-reduce via 16KB XOR-swizzled LDS, gates+c+h fused.
// ---------------------------------------------------------------------------
__global__ __launch_bounds__(256, 1)
void lstm_persistent(const h16* __restrict__ x16,
                     const float* __restrict__ weight,
                     const float* __restrict__ bias,
                     h16* __restrict__ h0r,
                     h16* __restrict__ h1r,
                     unsigned* __restrict__ bar)
{
  __shared__ h16  wlds[65536];   // 128 KB: [2 f][64 ks][64 lane][8]
  __shared__ float plds[4096];   // 16 KB : [4 wave][32 row][32 colS]

  const int wg    = blockIdx.x;
  const int layer = wg >> 7;
  const int j0    = (wg & 127) * 8;
  const int tid   = threadIdx.x;
  const int wave  = tid >> 6, lane = tid & 63;
  const int l15   = lane & 15, l16 = lane >> 4;

  // ---- one-time: pack this WG's weight slice fp32->fp16 into LDS ----
  {
    const float* wsrc = weight + (size_t)layer * 2 * GATES * HID;
    for (int c = tid; c < 8192; c += 256) {           // c = f*4096 + ks*64 + cl
      const int cl = c & 63, ks = (c >> 6) & 63, f = c >> 12;
      const int nl  = f * 16 + (cl & 15);
      const int col = (nl >> 3) * HID + j0 + (nl & 7);
      const int k   = ks * 32 + (cl >> 4) * 8;
      const float* p = wsrc + (k < HID ? (size_t)0 : (size_t)GATES * HID)
                            + (size_t)col * HID + (k & (HID - 1));
      h16x8 v;
#pragma unroll
      for (int e = 0; e < 8; ++e) v[e] = (h16)p[e];
      *(h16x8*)&wlds[(size_t)c * 8] = v;
    }
  }
  // combined bias for this thread's j (same j both m-rounds)
  float bc[4];
  {
    const int j = tid & 7;
#pragma unroll
    for (int gg = 0; gg < 4; ++gg) {
      const int col = gg * HID + j0 + j;
      bc[gg] = bias[(size_t)layer * 2 * GATES + col] +
               bias[(size_t)layer * 2 * GATES + GATES + col];
    }
  }
  float creg[2] = {0.f, 0.f};
  __syncthreads();

  for (int g = 0; g <= S_LEN; ++g) {
    const bool active = (layer == 0) ? (g < S_LEN) : (g >= 1);
    if (active) {
      const h16 *Alo, *Ahi;
      h16* Hout;
      if (layer == 0) {
        Alo  = x16 + (size_t)g * (BATCH * HID);
        Ahi  = h0r + (size_t)((g + 1) & 1) * (BATCH * HID);
        Hout = h0r + (size_t)(g & 1) * (BATCH * HID);
      } else {
        Alo  = h0r + (size_t)((g - 1) & 1) * (BATCH * HID);
        Ahi  = h1r + (size_t)(g & 1) * (BATCH * HID);
        Hout = h1r + (size_t)((g - 1) & 1) * (BATCH * HID);
      }
      const h16* Asrc = (wave < 2) ? Alo : Ahi;
      const int kbase = (wave & 1) * 512;

      const h16* arow[4];
#pragma unroll
      for (int i = 0; i < 4; ++i)
        arow[i] = Asrc + (size_t)(i * 16 + l15) * HID + kbase + l16 * 8;
      const h16* bbase = wlds + wave * 8192 + lane * 8;

      f32x4 acc[4][2];
#pragma unroll
      for (int i = 0; i < 4; ++i)
#pragma unroll
        for (int n2 = 0; n2 < 2; ++n2) acc[i][n2] = (f32x4)0.f;

#pragma unroll
      for (int s = 0; s < 16; ++s) {
        const h16x8 b0 = *(const h16x8*)(bbase + s * 512);
        const h16x8 b1 = *(const h16x8*)(bbase + 32768 + s * 512);
#pragma unroll
        for (int i = 0; i < 4; ++i) {
          const h16x8 a = *(const h16x8*)(arow[i] + s * 32);
          acc[i][0] = __builtin_amdgcn_mfma_f32_16x16x32_f16(a, b0, acc[i][0], 0, 0, 0);
          acc[i][1] = __builtin_amdgcn_mfma_f32_16x16x32_f16(a, b1, acc[i][1], 0, 0, 0);
        }
      }

      // ---- cross-wave reduce + activations, 2 m-rounds of 32 rows ----
#pragma unroll
      for (int r = 0; r < 2; ++r) {
#pragma unroll
        for (int ii = 0; ii < 2; ++ii) {
          const int i = r * 2 + ii;
#pragma unroll
          for (int n2 = 0; n2 < 2; ++n2)
#pragma unroll
            for (int q = 0; q < 4; ++q) {
              const int row = ii * 16 + l16 * 4 + q;            // 0..31
              const int colS = (n2 * 16 + l15) ^ ((row & 7) << 2);
              plds[(wave * 32 + row) * 32 + colS] = acc[i][n2][q];
            }
        }
        __syncthreads();
        {
          const int mr = tid >> 3, j = tid & 7;
          float gv[4];
#pragma unroll
          for (int gg = 0; gg < 4; ++gg) {
            const int colS = (gg * 8 + j) ^ ((mr & 7) << 2);
            float s = bc[gg];
#pragma unroll
            for (int w = 0; w < 4; ++w) s += plds[(w * 32 + mr) * 32 + colS];
            gv[gg] = s;
          }
          const float ig = 1.f / (1.f + __expf(-gv[0]));
          const float fg = 1.f / (1.f + __expf(-gv[1]));
          const float gt = 1.f - 2.f / (__expf(2.f * gv[2]) + 1.f);
          const float og = 1.f / (1.f + __expf(-gv[3]));
          const float cn = fg * creg[r] + ig * gt;
          creg[r] = cn;
          const float th = 1.f - 2.f / (__expf(2.f * cn) + 1.f);
          Hout[(size_t)(r * 32 + mr) * HID + j0 + j] = (h16)(og * th);
        }
        __syncthreads();
      }
    }
    grid_barrier(bar, g);
  }
}

// ---------------------------------------------------------------------------
// out[m][cls] = h[m] . fc_w[cls] + fc_b[cls]. One wave per output.
// ---------------------------------------------------------------------------
__global__ __launch_bounds__(256)
void fc_kernel(const h16* __restrict__ h,
               const float* __restrict__ fw,
               const float* __restrict__ fb,
               float* __restrict__ out)
{
  const int gw = (blockIdx.x * blockDim.x + threadIdx.x) >> 6;
  const int lane = threadIdx.x & 63;
  if (gw >= BATCH * 10) return;
  const int m = gw / 10, cls = gw % 10;
  float s = 0.f;
  for (int k = lane; k < HID; k += 64)
    s += (float)h[(size_t)m * HID + k] * fw[(size_t)cls * HID + k];
#pragma unroll
  for (int off = 32; off; off >>= 1) s += __shfl_down(s, off);
  if (lane == 0) out[m * 10 + cls] = s + fb[cls];
}

// ---------------------------------------------------------------------------
extern "C" void kernel_launch(void* const* d_in, const int* in_sizes, int n_in,
                              void* d_out, int out_size, void* d_ws, size_t ws_size,
                              hipStream_t stream)
{
  const float* x      = (const float*)d_in[0];   // [256][64][1024]
  const float* weight = (const float*)d_in[1];   // [2][2][4096][1024]
  const float* bias   = (const float*)d_in[2];   // [2][2][4096]
  const float* fc_w   = (const float*)d_in[3];   // [10][1024]
  const float* fc_b   = (const float*)d_in[4];   // [10]
  float* out = (float*)d_out;                    // [64][10]

  auto align = [](size_t v) { return (v + 255) & ~(size_t)255; };
  const size_t x16_sz = (size_t)S_LEN * BATCH * HID * sizeof(h16);  // 32 MB
  const size_t ring_sz = (size_t)2 * BATCH * HID * sizeof(h16);     // 256 KB

  char* p = (char*)d_ws;
  unsigned* bar = (unsigned*)p; p += 256;
  h16* x16 = (h16*)p; p += align(x16_sz);
  h16* h0r = (h16*)p; p += align(ring_sz);
  h16* h1r = (h16*)p; p += align(ring_sz);

  hipMemsetAsync(bar, 0, 256, stream);
  hipMemsetAsync(h0r, 0, ring_sz, stream);
  hipMemsetAsync(h1r, 0, ring_sz, stream);

  xconv_kernel<<<dim3(2048), 256, 0, stream>>>(x, x16);

  lstm_persistent<<<dim3(NBLK), dim3(256), 0, stream>>>(
      x16, weight, bias, h0r, h1r, bar);

  // final h of top layer: t = 255 -> ring slot 1
  fc_kernel<<<dim3((BATCH * 10 * 64) / 256), 256, 0, stream>>>(
      h1r + (size_t)BATCH * HID, fc_w, fc_b, out);
}

// Round 4
// 4538.946 us; speedup vs baseline: 2.3108x; 1.1848x over previous
//
#include <hip/hip_runtime.h>
#include <cstdint>
#include <cstddef>

#define S_LEN 256
#define BATCH 64
#define HID   1024
#define GATES 4096
#define NBLK  256
#define FLAG_STRIDE 32   // 32 uints = 128 B: one cache line per block's flag

typedef _Float16 h16;
typedef _Float16 h16x8 __attribute__((ext_vector_type(8)));
typedef _Float16 h16x4 __attribute__((ext_vector_type(4)));
typedef float    f32x4 __attribute__((ext_vector_type(4)));

// ---------------------------------------------------------------------------
// x fp32 -> fp16 (one pass)
// ---------------------------------------------------------------------------
__global__ __launch_bounds__(256)
void xconv_kernel(const float* __restrict__ x, h16* __restrict__ x16)
{
  const int n4 = S_LEN * BATCH * HID / 4;
  const int stride = gridDim.x * 256;
  for (int i = blockIdx.x * 256 + threadIdx.x; i < n4; i += stride) {
    f32x4 v = ((const f32x4*)x)[i];
    h16x4 o;
    o[0] = (h16)v[0]; o[1] = (h16)v[1]; o[2] = (h16)v[2]; o[3] = (h16)v[3];
    ((h16x4*)x16)[i] = o;
  }
}

// ---------------------------------------------------------------------------
// Flag-tree grid barrier: no atomic RMW contention.
//  - every block release-stores g+1 to its own 128B-padded flag
//  - block 0: 256 threads poll the 256 flags in parallel, then release go=g+1
//  - all blocks poll go (read-only), acquire-load once to invalidate L1/L2
// Monotone counters; flags zeroed per kernel_launch.
// ---------------------------------------------------------------------------
__device__ __forceinline__ void grid_barrier(unsigned* flags, unsigned* go,
                                             int g, int wg)
{
  __syncthreads();                      // drains vmcnt: block's stores are in L2
  const unsigned tgt = (unsigned)(g + 1);
  if (threadIdx.x == 0)
    __hip_atomic_store(&flags[wg * FLAG_STRIDE], tgt,
                       __ATOMIC_RELEASE, __HIP_MEMORY_SCOPE_AGENT);
  if (wg == 0) {
    while (__hip_atomic_load(&flags[threadIdx.x * FLAG_STRIDE],
                             __ATOMIC_RELAXED, __HIP_MEMORY_SCOPE_AGENT) < tgt) {}
    (void)__hip_atomic_load(&flags[threadIdx.x * FLAG_STRIDE],
                            __ATOMIC_ACQUIRE, __HIP_MEMORY_SCOPE_AGENT);
    __syncthreads();
    if (threadIdx.x == 0)
      __hip_atomic_store(go, tgt, __ATOMIC_RELEASE, __HIP_MEMORY_SCOPE_AGENT);
  }
  if (threadIdx.x == 0) {
    while (__hip_atomic_load(go, __ATOMIC_RELAXED,
                             __HIP_MEMORY_SCOPE_AGENT) < tgt) {}
    (void)__hip_atomic_load(go, __ATOMIC_ACQUIRE, __HIP_MEMORY_SCOPE_AGENT);
  }
  __syncthreads();
}

// ---------------------------------------------------------------------------
// Persistent 2-layer pipelined LSTM. 256 WGs x 256 thr (1 per CU).
// WG wg: layer = wg>>7, owns hidden cols j0..j0+7 (32 gate-cols).
// Weights (K=2048 = [W_ih | W_hh]) packed fp16 in 128KB LDS, loaded once.
// Step g: layer0 computes t=g (g<256), layer1 computes t=g-1 (g>=1).
// Wave w covers K-slice w*512..: waves 0-1 input part, waves 2-3 hidden part.
// Cross-wave K-reduce via 16KB XOR-swizzled LDS, gates+c+h fused.
// ---------------------------------------------------------------------------
__global__ __launch_bounds__(256, 1)
void lstm_persistent(const h16* __restrict__ x16,
                     const float* __restrict__ weight,
                     const float* __restrict__ bias,
                     h16* __restrict__ h0r,
                     h16* __restrict__ h1r,
                     unsigned* __restrict__ flags,
                     unsigned* __restrict__ go)
{
  __shared__ h16  wlds[65536];   // 128 KB: [2 f][64 ks][64 lane][8]
  __shared__ float plds[4096];   // 16 KB : [4 wave][32 row][32 colS]

  const int wg    = blockIdx.x;
  const int layer = wg >> 7;
  const int j0    = (wg & 127) * 8;
  const int tid   = threadIdx.x;
  const int wave  = tid >> 6, lane = tid & 63;
  const int l15   = lane & 15, l16 = lane >> 4;

  // ---- one-time: pack this WG's weight slice fp32->fp16 into LDS ----
  {
    const float* wsrc = weight + (size_t)layer * 2 * GATES * HID;
    for (int c = tid; c < 8192; c += 256) {           // c = f*4096 + ks*64 + cl
      const int cl = c & 63, ks = (c >> 6) & 63, f = c >> 12;
      const int nl  = f * 16 + (cl & 15);
      const int col = (nl >> 3) * HID + j0 + (nl & 7);
      const int k   = ks * 32 + (cl >> 4) * 8;
      const float* p = wsrc + (k < HID ? (size_t)0 : (size_t)GATES * HID)
                            + (size_t)col * HID + (k & (HID - 1));
      h16x8 v;
#pragma unroll
      for (int e = 0; e < 8; ++e) v[e] = (h16)p[e];
      *(h16x8*)&wlds[(size_t)c * 8] = v;
    }
  }
  // combined bias for this thread's j (same j both m-rounds)
  float bc[4];
  {
    const int j = tid & 7;
#pragma unroll
    for (int gg = 0; gg < 4; ++gg) {
      const int col = gg * HID + j0 + j;
      bc[gg] = bias[(size_t)layer * 2 * GATES + col] +
               bias[(size_t)layer * 2 * GATES + GATES + col];
    }
  }
  float creg[2] = {0.f, 0.f};
  __syncthreads();

  for (int g = 0; g <= S_LEN; ++g) {
    const bool active = (layer == 0) ? (g < S_LEN) : (g >= 1);
    if (active) {
      const h16 *Alo, *Ahi;
      h16* Hout;
      if (layer == 0) {
        Alo  = x16 + (size_t)g * (BATCH * HID);
        Ahi  = h0r + (size_t)((g + 1) & 1) * (BATCH * HID);
        Hout = h0r + (size_t)(g & 1) * (BATCH * HID);
      } else {
        Alo  = h0r + (size_t)((g - 1) & 1) * (BATCH * HID);
        Ahi  = h1r + (size_t)(g & 1) * (BATCH * HID);
        Hout = h1r + (size_t)((g - 1) & 1) * (BATCH * HID);
      }
      const h16* Asrc = (wave < 2) ? Alo : Ahi;
      const int kbase = (wave & 1) * 512;

      const h16* arow[4];
#pragma unroll
      for (int i = 0; i < 4; ++i)
        arow[i] = Asrc + (size_t)(i * 16 + l15) * HID + kbase + l16 * 8;
      const h16* bbase = wlds + wave * 8192 + lane * 8;

      f32x4 acc[4][2];
#pragma unroll
      for (int i = 0; i < 4; ++i)
#pragma unroll
        for (int n2 = 0; n2 < 2; ++n2) acc[i][n2] = (f32x4)0.f;

#pragma unroll
      for (int s = 0; s < 16; ++s) {
        const h16x8 b0 = *(const h16x8*)(bbase + s * 512);
        const h16x8 b1 = *(const h16x8*)(bbase + 32768 + s * 512);
#pragma unroll
        for (int i = 0; i < 4; ++i) {
          const h16x8 a = *(const h16x8*)(arow[i] + s * 32);
          acc[i][0] = __builtin_amdgcn_mfma_f32_16x16x32_f16(a, b0, acc[i][0], 0, 0, 0);
          acc[i][1] = __builtin_amdgcn_mfma_f32_16x16x32_f16(a, b1, acc[i][1], 0, 0, 0);
        }
      }

      // ---- cross-wave reduce + activations, 2 m-rounds of 32 rows ----
#pragma unroll
      for (int r = 0; r < 2; ++r) {
#pragma unroll
        for (int ii = 0; ii < 2; ++ii) {
          const int i = r * 2 + ii;
#pragma unroll
          for (int n2 = 0; n2 < 2; ++n2)
#pragma unroll
            for (int q = 0; q < 4; ++q) {
              const int row = ii * 16 + l16 * 4 + q;            // 0..31
              const int colS = (n2 * 16 + l15) ^ ((row & 7) << 2);
              plds[(wave * 32 + row) * 32 + colS] = acc[i][n2][q];
            }
        }
        __syncthreads();
        {
          const int mr = tid >> 3, j = tid & 7;
          float gv[4];
#pragma unroll
          for (int gg = 0; gg < 4; ++gg) {
            const int colS = (gg * 8 + j) ^ ((mr & 7) << 2);
            float s = bc[gg];
#pragma unroll
            for (int w = 0; w < 4; ++w) s += plds[(w * 32 + mr) * 32 + colS];
            gv[gg] = s;
          }
          const float ig = 1.f / (1.f + __expf(-gv[0]));
          const float fg = 1.f / (1.f + __expf(-gv[1]));
          const float gt = 1.f - 2.f / (__expf(2.f * gv[2]) + 1.f);
          const float og = 1.f / (1.f + __expf(-gv[3]));
          const float cn = fg * creg[r] + ig * gt;
          creg[r] = cn;
          const float th = 1.f - 2.f / (__expf(2.f * cn) + 1.f);
          Hout[(size_t)(r * 32 + mr) * HID + j0 + j] = (h16)(og * th);
        }
        __syncthreads();
      }
    }
    grid_barrier(flags, go, g, wg);
  }
}

// ---------------------------------------------------------------------------
// out[m][cls] = h[m] . fc_w[cls] + fc_b[cls]. One wave per output.
// ---------------------------------------------------------------------------
__global__ __launch_bounds__(256)
void fc_kernel(const h16* __restrict__ h,
               const float* __restrict__ fw,
               const float* __restrict__ fb,
               float* __restrict__ out)
{
  const int gw = (blockIdx.x * blockDim.x + threadIdx.x) >> 6;
  const int lane = threadIdx.x & 63;
  if (gw >= BATCH * 10) return;
  const int m = gw / 10, cls = gw % 10;
  float s = 0.f;
  for (int k = lane; k < HID; k += 64)
    s += (float)h[(size_t)m * HID + k] * fw[(size_t)cls * HID + k];
#pragma unroll
  for (int off = 32; off; off >>= 1) s += __shfl_down(s, off);
  if (lane == 0) out[m * 10 + cls] = s + fb[cls];
}

// ---------------------------------------------------------------------------
extern "C" void kernel_launch(void* const* d_in, const int* in_sizes, int n_in,
                              void* d_out, int out_size, void* d_ws, size_t ws_size,
                              hipStream_t stream)
{
  const float* x      = (const float*)d_in[0];   // [256][64][1024]
  const float* weight = (const float*)d_in[1];   // [2][2][4096][1024]
  const float* bias   = (const float*)d_in[2];   // [2][2][4096]
  const float* fc_w   = (const float*)d_in[3];   // [10][1024]
  const float* fc_b   = (const float*)d_in[4];   // [10]
  float* out = (float*)d_out;                    // [64][10]

  auto align = [](size_t v) { return (v + 255) & ~(size_t)255; };
  const size_t flags_sz = (size_t)NBLK * FLAG_STRIDE * sizeof(unsigned); // 32 KB
  const size_t x16_sz  = (size_t)S_LEN * BATCH * HID * sizeof(h16);      // 32 MB
  const size_t ring_sz = (size_t)2 * BATCH * HID * sizeof(h16);          // 256 KB

  char* p = (char*)d_ws;
  unsigned* flags = (unsigned*)p; p += align(flags_sz);
  unsigned* go    = (unsigned*)p; p += 256;
  h16* x16 = (h16*)p; p += align(x16_sz);
  h16* h0r = (h16*)p; p += align(ring_sz);
  h16* h1r = (h16*)p; p += align(ring_sz);

  hipMemsetAsync(flags, 0, flags_sz, stream);
  hipMemsetAsync(go, 0, 256, stream);
  hipMemsetAsync(h0r, 0, ring_sz, stream);
  hipMemsetAsync(h1r, 0, ring_sz, stream);

  xconv_kernel<<<dim3(2048), 256, 0, stream>>>(x, x16);

  lstm_persistent<<<dim3(NBLK), dim3(256), 0, stream>>>(
      x16, weight, bias, h0r, h1r, flags, go);

  // final h of top layer: t = 255 -> ring slot 1
  fc_kernel<<<dim3((BATCH * 10 * 64) / 256), 256, 0, stream>>>(
      h1r + (size_t)BATCH * HID, fc_w, fc_b, out);
}